// Round 8
// baseline (102.636 us; speedup 1.0000x reference)
//
#include <hip/hip_runtime.h>
#include <math.h>
#include <stdint.h>

#define EMBED 512
#define HID 16
#define SEQ 1024

typedef unsigned short u16;
typedef __attribute__((ext_vector_type(8))) __bf16 bf16x8;
typedef __attribute__((ext_vector_type(4))) float f32x4;

__device__ __forceinline__ u16 f2bf(float f) {
    unsigned u = __float_as_uint(f);
    unsigned r = (u + 0x7FFFu + ((u >> 16) & 1u)) >> 16;   // RNE
    return (u16)r;
}
__device__ __forceinline__ float bf2f(u16 h) {
    return __uint_as_float(((unsigned)h) << 16);
}
__device__ __forceinline__ void gload16(const void* g, void* d) {
    __builtin_amdgcn_global_load_lds(
        reinterpret_cast<const __attribute__((address_space(1))) unsigned int*>(
            reinterpret_cast<uintptr_t>(g)),
        reinterpret_cast<__attribute__((address_space(3))) unsigned int*>(
            reinterpret_cast<uintptr_t>(d)),
        16, 0, 0);
}

// ---------------- Kernel 1: fold W1 into Wq/Wk (+fused Wv hi/lo split) ----------------
__global__ __launch_bounds__(256) void wc_kernel(
    const float* __restrict__ Wq, const float* __restrict__ Wk,
    const float* __restrict__ W1, const float* __restrict__ Wvm,
    float* __restrict__ WcT, u16* __restrict__ wv_hi, u16* __restrict__ wv_lo)
{
    __shared__ float w1s[EMBED];
    int t = threadIdx.x;
    if (blockIdx.x >= 32) {
        int i = (blockIdx.x - 32) * 256 + t;       // float4 idx < 65536
        float4 v = ((const float4*)Wvm)[i];
        u16 h0 = f2bf(v.x), h1 = f2bf(v.y), h2 = f2bf(v.z), h3 = f2bf(v.w);
        ((ushort4*)wv_hi)[i] = make_ushort4(h0, h1, h2, h3);
        ((ushort4*)wv_lo)[i] = make_ushort4(f2bf(v.x - bf2f(h0)), f2bf(v.y - bf2f(h1)),
                                            f2bf(v.z - bf2f(h2)), f2bf(v.w - bf2f(h3)));
        return;
    }
    int h2 = blockIdx.x;              // 0..31
    int ab = h2 >> 4, h = h2 & 15;
    const float* Wmat = ab ? Wk : Wq;
    const float* w1row = W1 + (size_t)h * (2 * EMBED) + ab * EMBED;
    for (int f = t; f < EMBED; f += 256) w1s[f] = w1row[f];
    __syncthreads();
    float acc0 = 0.f, acc1 = 0.f;
    int e0 = t, e1 = t + 256;
    for (int f = 0; f < EMBED; ++f) {
        float w = w1s[f];
        acc0 += w * Wmat[(size_t)f * EMBED + e0];
        acc1 += w * Wmat[(size_t)f * EMBED + e1];
    }
    WcT[(size_t)e0 * 32 + h2] = acc0;
    WcT[(size_t)e1 * 32 + h2] = acc1;
}

// ---------------- Kernel 2: A/Bm projections (+fused x_hi split) ----------------
__global__ __launch_bounds__(256) void ab_kernel(
    const float* __restrict__ x, const float* __restrict__ WcT,
    const float* __restrict__ b1,
    float* __restrict__ A, float* __restrict__ Bm, u16* __restrict__ x_hi)
{
    __shared__ float xs[8][EMBED];
    __shared__ float wcs[EMBED * 32];
    int t = threadIdx.x;
    int s0 = blockIdx.x * 8;
    #pragma unroll
    for (int i = 0; i < 4; ++i) {
        int idx = t + i * 256;
        int row = idx >> 7, c4 = idx & 127;
        float4 vv = *(const float4*)(x + (size_t)(s0 + row) * EMBED + c4 * 4);
        *(float4*)&xs[row][c4 * 4] = vv;
        u16 h0 = f2bf(vv.x), h1 = f2bf(vv.y), h2 = f2bf(vv.z), h3 = f2bf(vv.w);
        ((ushort4*)x_hi)[(s0 + row) * 128 + c4] = make_ushort4(h0, h1, h2, h3);
    }
    #pragma unroll
    for (int i = 0; i < 16; ++i) {
        int idx = t + i * 256;
        ((float4*)wcs)[idx] = ((const float4*)WcT)[idx];
    }
    __syncthreads();
    int r = t >> 5, h2 = t & 31;
    const float* xr = xs[r];
    float acc = 0.f;
    #pragma unroll 8
    for (int k = 0; k < EMBED; ++k)
        acc += xr[k] * wcs[k * 32 + h2];
    int s = s0 + r;
    if (h2 < HID) A[(size_t)s * HID + h2] = acc + b1[h2];
    else          Bm[(size_t)s * HID + (h2 - 16)] = acc;
}

// ---------------- staging helpers (128B-row tiles, XOR swizzle; proven) ----------------
template<int NR>
__device__ __forceinline__ void stageR(const u16* src, int ld, int kt,
                                       u16* ldsb, int t)
{
    int kb0 = kt << 7;
    #pragma unroll
    for (int i = 0; i < NR / 32; ++i) {
        int row  = i * 32 + (t >> 3);
        int colb = (((t & 7) ^ ((t >> 3) & 7)) << 4);
        const char* g = (const char*)src + (size_t)row * ((size_t)ld * 2) + kb0 + colb;
        gload16(g, (char*)ldsb + i * 4096 + ((t >> 6) << 10) + ((t & 63) << 4));
    }
}
__device__ __forceinline__ bf16x8 ldfrag(const u16* ldsb, int r, int s) {
    return *(const bf16x8*)((const char*)ldsb + r * 128 + (((s ^ (r & 7))) << 4));
}

// ---------------- Kernel 3: VT_hi[512][4096] = Wv(split) x X_hi^T ----------------
// 2-term: (wh+wl)*xh — x quantization error only. 64x64 tile, BK=64, dbuf.
__global__ __launch_bounds__(256, 2) void vgemm_kernel(
    const u16* __restrict__ Ah, const u16* __restrict__ Al,
    const u16* __restrict__ Bh, u16* __restrict__ outH)
{
    constexpr int TOFF = 64 * 64;
    __shared__ __attribute__((aligned(16))) u16 lds[2][3 * TOFF];   // 48 KB
    int t = threadIdx.x;
    int l = t & 63, wid = t >> 6;
    int wm = (wid >> 1) * 32, wn = (wid & 1) * 32;
    int m0 = blockIdx.y * 64, n0 = blockIdx.x * 64;
    const u16* pAh = Ah + (size_t)m0 * EMBED;
    const u16* pAl = Al + (size_t)m0 * EMBED;
    const u16* pBh = Bh + (size_t)n0 * EMBED;
    f32x4 acc[2][2] = {};

    auto STAGE = [&](int buf, int kt) {
        stageR<64>(pAh, EMBED, kt, lds[buf], t);
        stageR<64>(pAl, EMBED, kt, lds[buf] + TOFF, t);
        stageR<64>(pBh, EMBED, kt, lds[buf] + 2 * TOFF, t);
    };
    auto COMPUTE = [&](int buf) {
        #pragma unroll
        for (int kk = 0; kk < 2; ++kk) {
            int sb = (kk << 2) + (l >> 4);
            bf16x8 ah[2], al2[2], bh[2];
            #pragma unroll
            for (int mf = 0; mf < 2; ++mf) {
                int r = wm + mf * 16 + (l & 15);
                ah[mf]  = ldfrag(lds[buf], r, sb);
                al2[mf] = ldfrag(lds[buf] + TOFF, r, sb);
            }
            #pragma unroll
            for (int nf = 0; nf < 2; ++nf)
                bh[nf] = ldfrag(lds[buf] + 2 * TOFF, wn + nf * 16 + (l & 15), sb);
            #pragma unroll
            for (int mf = 0; mf < 2; ++mf)
                #pragma unroll
                for (int nf = 0; nf < 2; ++nf) {
                    acc[mf][nf] = __builtin_amdgcn_mfma_f32_16x16x32_bf16(ah[mf],  bh[nf], acc[mf][nf], 0, 0, 0);
                    acc[mf][nf] = __builtin_amdgcn_mfma_f32_16x16x32_bf16(al2[mf], bh[nf], acc[mf][nf], 0, 0, 0);
                }
        }
    };

    STAGE(0, 0);
    __syncthreads();
    int cur = 0;
    for (int kt = 0; kt + 1 < 8; ++kt) {
        STAGE(cur ^ 1, kt + 1);
        COMPUTE(cur);
        __syncthreads();
        cur ^= 1;
    }
    COMPUTE(cur);

    int cr = (l >> 4) << 2, cc = l & 15;
    #pragma unroll
    for (int mf = 0; mf < 2; ++mf)
        #pragma unroll
        for (int nf = 0; nf < 2; ++nf)
            #pragma unroll
            for (int r = 0; r < 4; ++r)
                outH[(size_t)(m0 + wm + mf * 16 + cr + r) * 4096
                     + n0 + wn + nf * 16 + cc] = f2bf(acc[mf][nf][r]);
}

// ---------------- Kernel 4: fused logits+softmax+PV (pipelined) ----------------
// Fixed-max softmax: s < S0 = sum max(-2w,0), p~ = exp2((s-S0)*log2e) in (0,1].
// V is WAVE-LOCAL in LDS (each wave stages+reads its own 128 d-rows -> no barrier).
// Bm goes global->VGPR; its register-dep vmcnt wait drains V(c) (issued older)
// while V(c+1) prefetch stays in flight. ONE raw s_barrier per chunk (P-ready).
__global__ __launch_bounds__(256, 1) void fused_kernel(
    const float* __restrict__ A, const float* __restrict__ Bm,
    const float* __restrict__ w2, const u16* __restrict__ VT,
    float* __restrict__ out)
{
    __shared__ __attribute__((aligned(16))) u16 Vl[2][4][128 * 32];  // 2buf x wave x 8KB
    __shared__ __attribute__((aligned(16))) u16 Pl[2][2][16 * 40];   // 80B rows
    __shared__ float sred[4][16];
    __shared__ float srow[16];

    const float K2 = 2.8853900817779268f;   // 2*log2(e)
    const float L2E = 1.4426950408889634f;
    int t = threadIdx.x;
    int l = t & 63, w = t >> 6;
    int n = blockIdx.x;                      // 0..255
    int b = (n >> 1) & 3;                    // XCD x -> b = x>>1 (L2-affine)
    int m0 = ((((n & 1) << 5) | (n >> 3))) << 4;
    int prow = t & 15, pslot = t >> 4;

    const float4* Ar = (const float4*)(A + (size_t)(b * SEQ + m0 + prow) * HID);
    float4 a0 = Ar[0], a1 = Ar[1], a2 = Ar[2], a3 = Ar[3];
    float4 k0, k1, k2, k3;
    k0.x = K2*a0.x; k0.y = K2*a0.y; k0.z = K2*a0.z; k0.w = K2*a0.w;
    k1.x = K2*a1.x; k1.y = K2*a1.y; k1.z = K2*a1.z; k1.w = K2*a1.w;
    k2.x = K2*a2.x; k2.y = K2*a2.y; k2.z = K2*a2.z; k2.w = K2*a2.w;
    k3.x = K2*a3.x; k3.y = K2*a3.y; k3.z = K2*a3.z; k3.w = K2*a3.w;

    const float4* Wq4 = (const float4*)w2;
    float4 u0 = Wq4[0], u1 = Wq4[1], u2 = Wq4[2], u3 = Wq4[3];
    float Pa1 = -2.f*u0.x, Pa2 = -2.f*u0.y, Pas = Pa1 + Pa2;
    float Pb1 = -2.f*u0.z, Pb2 = -2.f*u0.w, Pbs = Pb1 + Pb2;
    float Pc1 = -2.f*u1.x, Pc2 = -2.f*u1.y, Pcs = Pc1 + Pc2;
    float Pd1 = -2.f*u1.z, Pd2 = -2.f*u1.w, Pds = Pd1 + Pd2;
    float Pe1 = -2.f*u2.x, Pe2 = -2.f*u2.y, Pes = Pe1 + Pe2;
    float Pf1 = -2.f*u2.z, Pf2 = -2.f*u2.w, Pfs = Pf1 + Pf2;
    float Pg1 = -2.f*u3.x, Pg2 = -2.f*u3.y, Pgs = Pg1 + Pg2;
    float Ph1 = -2.f*u3.z, Ph2 = -2.f*u3.w, Phs = Ph1 + Ph2;
    float S0 = fmaxf(Pa1,0.f)+fmaxf(Pa2,0.f)+fmaxf(Pb1,0.f)+fmaxf(Pb2,0.f)
             + fmaxf(Pc1,0.f)+fmaxf(Pc2,0.f)+fmaxf(Pd1,0.f)+fmaxf(Pd2,0.f)
             + fmaxf(Pe1,0.f)+fmaxf(Pe2,0.f)+fmaxf(Pf1,0.f)+fmaxf(Pf2,0.f)
             + fmaxf(Pg1,0.f)+fmaxf(Pg2,0.f)+fmaxf(Ph1,0.f)+fmaxf(Ph2,0.f);

    auto calc_lg = [&](float4 v0, float4 v1, float4 v2, float4 v3) -> float {
        float s = 0.f;
#define PAIRF(bx, by, kx, ky, P1, P2, PS) { \
        float e1 = __builtin_amdgcn_exp2f(fmaf(K2, (bx), (kx))); \
        float e2 = __builtin_amdgcn_exp2f(fmaf(K2, (by), (ky))); \
        float dd = fmaf(e1, e2, e1) + e2 + 1.0f; \
        float nn = fmaf((P1), e2, (PS)); nn = fmaf((P2), e1, nn); \
        s = fmaf(nn, __builtin_amdgcn_rcpf(dd), s); }
        PAIRF(v0.x, v0.y, k0.x, k0.y, Pa1, Pa2, Pas)
        PAIRF(v0.z, v0.w, k0.z, k0.w, Pb1, Pb2, Pbs)
        PAIRF(v1.x, v1.y, k1.x, k1.y, Pc1, Pc2, Pcs)
        PAIRF(v1.z, v1.w, k1.z, k1.w, Pd1, Pd2, Pds)
        PAIRF(v2.x, v2.y, k2.x, k2.y, Pe1, Pe2, Pes)
        PAIRF(v2.z, v2.w, k2.z, k2.w, Pf1, Pf2, Pfs)
        PAIRF(v3.x, v3.y, k3.x, k3.y, Pg1, Pg2, Pgs)
        PAIRF(v3.z, v3.w, k3.z, k3.w, Ph1, Ph2, Phs)
#undef PAIRF
        return s;
    };

    // wave-local V staging: wave w owns d-rows [128w, 128w+128)
    auto stageV = [&](int buf, int c) {
        size_t colbase = ((size_t)b << 10) + ((size_t)c << 5);   // u16 col in VT
        #pragma unroll
        for (int i = 0; i < 8; ++i) {
            int rl = (i << 4) + (l >> 2);                        // row_local 0..127
            int f_ = (rl >> 1) & 3;
            int sl = ((l & 3) - f_) & 3;                         // inverse slot swizzle
            const u16* g = VT + (size_t)((w << 7) + rl) * 4096 + colbase + (sl << 3);
            gload16(g, (char*)&Vl[buf][w][0] + (i << 10) + (l << 4));
        }
    };

    f32x4 acc[8] = {};
    float s_part = 0.f;

    stageV(0, 0);
    const float* BmB = Bm + ((size_t)(b << 10) + (pslot << 1)) * HID;

    #pragma unroll 1
    for (int c = 0; c < 32; ++c) {
        int pb = c & 1;
        // 1. Bm(c) -> regs (issued BEFORE V(c+1): its wait drains V(c) only)
        const float4* Bp = (const float4*)(BmB + (size_t)(c << 5) * HID);
        float4 q0 = Bp[0], q1 = Bp[1], q2 = Bp[2], q3 = Bp[3];
        float4 r0 = Bp[4], r1 = Bp[5], r2 = Bp[6], r3 = Bp[7];
        __builtin_amdgcn_sched_barrier(0);
        // 2. prefetch V(c+1)
        if (c + 1 < 32) stageV(pb ^ 1, c + 1);
        __builtin_amdgcn_sched_barrier(0);
        // 3. logits (first q/r use -> compiler vmcnt wait -> V(c) landed too)
        float lg0 = calc_lg(q0, q1, q2, q3);
        float lg1 = calc_lg(r0, r1, r2, r3);
        float p0 = __builtin_amdgcn_exp2f((lg0 - S0) * L2E);
        float p1 = __builtin_amdgcn_exp2f((lg1 - S0) * L2E);
        s_part += p0 + p1;
        u16 h0 = f2bf(p0), lo0 = f2bf(p0 - bf2f(h0));
        u16 h1 = f2bf(p1), lo1 = f2bf(p1 - bf2f(h1));
        *(ushort2*)((char*)&Pl[pb][0][0] + prow * 80 + pslot * 4) = make_ushort2(h0, h1);
        *(ushort2*)((char*)&Pl[pb][1][0] + prow * 80 + pslot * 4) = make_ushort2(lo0, lo1);
        asm volatile("s_waitcnt lgkmcnt(0)" ::: "memory");
        __builtin_amdgcn_s_barrier();            // P(c) ready (sole barrier/chunk)
        __builtin_amdgcn_sched_barrier(0);
        // 4. PV MFMA (own-wave V region; P cross-wave, protected by barrier)
        bf16x8 pah = *(const bf16x8*)((const char*)&Pl[pb][0][0] + (l & 15) * 80 + ((l >> 4) << 4));
        bf16x8 pal = *(const bf16x8*)((const char*)&Pl[pb][1][0] + (l & 15) * 80 + ((l >> 4) << 4));
        #pragma unroll
        for (int nf = 0; nf < 8; ++nf) {
            int rl = (nf << 4) + (l & 15);
            int phys = ((l >> 4) + ((rl >> 1) & 3)) & 3;
            bf16x8 vb = *(const bf16x8*)((const char*)&Vl[pb][w][0] + rl * 64 + (phys << 4));
            acc[nf] = __builtin_amdgcn_mfma_f32_16x16x32_bf16(pah, vb, acc[nf], 0, 0, 0);
            acc[nf] = __builtin_amdgcn_mfma_f32_16x16x32_bf16(pal, vb, acc[nf], 0, 0, 0);
        }
    }

    // row-sum reduce
    float sv = s_part;
    sv += __shfl_xor(sv, 16);
    sv += __shfl_xor(sv, 32);
    if (l < 16) sred[w][l] = sv;
    __syncthreads();
    if (t < 16) srow[t] = (sred[0][t] + sred[1][t]) + (sred[2][t] + sred[3][t]);
    __syncthreads();
    int rr = (l >> 4) << 2;
    float i0 = __fdividef(1.f, srow[rr + 0]);
    float i1 = __fdividef(1.f, srow[rr + 1]);
    float i2 = __fdividef(1.f, srow[rr + 2]);
    float i3 = __fdividef(1.f, srow[rr + 3]);
    #pragma unroll
    for (int nf = 0; nf < 8; ++nf) {
        size_t base = (size_t)(b * SEQ + m0 + rr) * EMBED + (w << 7) + (nf << 4) + (l & 15);
        out[base]             = acc[nf][0] * i0;
        out[base + EMBED]     = acc[nf][1] * i1;
        out[base + 2 * EMBED] = acc[nf][2] * i2;
        out[base + 3 * EMBED] = acc[nf][3] * i3;
    }
}

extern "C" void kernel_launch(void* const* d_in, const int* in_sizes, int n_in,
                              void* d_out, int out_size, void* d_ws, size_t ws_size,
                              hipStream_t stream) {
    const float* x   = (const float*)d_in[0];
    const float* Wq  = (const float*)d_in[1];
    const float* Wk  = (const float*)d_in[2];
    const float* Wvm = (const float*)d_in[3];
    const float* W1  = (const float*)d_in[4];
    const float* b1  = (const float*)d_in[5];
    const float* w2  = (const float*)d_in[6];
    // d_in[7] = b2: softmax shift-invariant, unused.

    char* ws = (char*)d_ws;
    float* WcT   = (float*)(ws + 0);          //    65,536 B
    float* A     = (float*)(ws + 65536);      //   262,144 B
    float* Bm    = (float*)(ws + 327680);     //   262,144 B
    u16*   VT_hi = (u16*)(ws + 589824);       // 4,194,304 B  [512][4096]
    u16*   x_hi  = (u16*)(ws + 4784128);      // 4,194,304 B  [4096][512]
    u16*   wv_hi = (u16*)(ws + 8978432);      //   524,288 B
    u16*   wv_lo = (u16*)(ws + 9502720);      //   524,288 B
    float* out   = (float*)d_out;

    hipLaunchKernelGGL(wc_kernel, dim3(288), dim3(256), 0, stream,
                       Wq, Wk, W1, Wvm, WcT, wv_hi, wv_lo);
    hipLaunchKernelGGL(ab_kernel, dim3(512), dim3(256), 0, stream,
                       x, WcT, b1, A, Bm, x_hi);
    hipLaunchKernelGGL(vgemm_kernel, dim3(64, 8), dim3(256), 0, stream,
                       wv_hi, wv_lo, x_hi, VT_hi);
    hipLaunchKernelGGL(fused_kernel, dim3(256), dim3(256), 0, stream,
                       A, Bm, w2, VT_hi, out);
}

// Round 9
// 84.959 us; speedup vs baseline: 1.2081x; 1.2081x over previous
//
#include <hip/hip_runtime.h>
#include <math.h>
#include <stdint.h>

#define EMBED 512
#define HID 16
#define SEQ 1024

typedef unsigned short u16;
typedef __attribute__((ext_vector_type(8))) __bf16 bf16x8;
typedef __attribute__((ext_vector_type(4))) float f32x4;

__device__ __forceinline__ u16 f2bf(float f) {
    unsigned u = __float_as_uint(f);
    unsigned r = (u + 0x7FFFu + ((u >> 16) & 1u)) >> 16;   // RNE
    return (u16)r;
}
__device__ __forceinline__ float bf2f(u16 h) {
    return __uint_as_float(((unsigned)h) << 16);
}
__device__ __forceinline__ void gload16(const void* g, void* d) {
    __builtin_amdgcn_global_load_lds(
        reinterpret_cast<const __attribute__((address_space(1))) unsigned int*>(
            reinterpret_cast<uintptr_t>(g)),
        reinterpret_cast<__attribute__((address_space(3))) unsigned int*>(
            reinterpret_cast<uintptr_t>(d)),
        16, 0, 0);
}

// ---------------- Kernel 1: fold W1 into Wq/Wk (+fused Wv hi/lo split) ----------------
// blocks 0..63: WcT fold (h2 x e-half); blocks 64..319: Wv split.
__global__ __launch_bounds__(256) void wc_kernel(
    const float* __restrict__ Wq, const float* __restrict__ Wk,
    const float* __restrict__ W1, const float* __restrict__ Wvm,
    float* __restrict__ WcT, u16* __restrict__ wv_hi, u16* __restrict__ wv_lo)
{
    __shared__ float w1s[EMBED];
    int t = threadIdx.x;
    if (blockIdx.x >= 64) {
        int i = (blockIdx.x - 64) * 256 + t;       // float4 idx < 65536
        float4 v = ((const float4*)Wvm)[i];
        u16 h0 = f2bf(v.x), h1 = f2bf(v.y), h2 = f2bf(v.z), h3 = f2bf(v.w);
        ((ushort4*)wv_hi)[i] = make_ushort4(h0, h1, h2, h3);
        ((ushort4*)wv_lo)[i] = make_ushort4(f2bf(v.x - bf2f(h0)), f2bf(v.y - bf2f(h1)),
                                            f2bf(v.z - bf2f(h2)), f2bf(v.w - bf2f(h3)));
        return;
    }
    int h2 = blockIdx.x >> 1;         // 0..31
    int ab = h2 >> 4, h = h2 & 15;
    const float* Wmat = ab ? Wk : Wq;
    const float* w1row = W1 + (size_t)h * (2 * EMBED) + ab * EMBED;
    for (int f = t; f < EMBED; f += 256) w1s[f] = w1row[f];
    __syncthreads();
    int e0 = ((blockIdx.x & 1) << 8) + t;
    float acc = 0.f;
    #pragma unroll 16
    for (int f = 0; f < EMBED; ++f)
        acc += w1s[f] * Wmat[(size_t)f * EMBED + e0];
    WcT[(size_t)e0 * 32 + h2] = acc;
}

// ---------------- Kernel 2: EA/EB projections (+fused x_hi split) ----------------
// EA[s][h] = exp2(K2*(x@Wc_a^T + b1)), EB[s][h] = exp2(K2*(x@Wc_b^T)).
__global__ __launch_bounds__(256) void ab_kernel(
    const float* __restrict__ x, const float* __restrict__ WcT,
    const float* __restrict__ b1,
    float* __restrict__ EA, float* __restrict__ EB, u16* __restrict__ x_hi)
{
    const float K2 = 2.8853900817779268f;   // 2*log2(e)
    __shared__ float xs[8][EMBED];
    __shared__ float wcs[EMBED * 32];
    int t = threadIdx.x;
    int s0 = blockIdx.x * 8;
    #pragma unroll
    for (int i = 0; i < 4; ++i) {
        int idx = t + i * 256;
        int row = idx >> 7, c4 = idx & 127;
        float4 vv = *(const float4*)(x + (size_t)(s0 + row) * EMBED + c4 * 4);
        *(float4*)&xs[row][c4 * 4] = vv;
        u16 h0 = f2bf(vv.x), h1 = f2bf(vv.y), h2 = f2bf(vv.z), h3 = f2bf(vv.w);
        ((ushort4*)x_hi)[(s0 + row) * 128 + c4] = make_ushort4(h0, h1, h2, h3);
    }
    #pragma unroll
    for (int i = 0; i < 16; ++i) {
        int idx = t + i * 256;
        ((float4*)wcs)[idx] = ((const float4*)WcT)[idx];
    }
    __syncthreads();
    int r = t >> 5, h2 = t & 31;
    const float* xr = xs[r];
    float acc = 0.f;
    #pragma unroll 8
    for (int k = 0; k < EMBED; ++k)
        acc += xr[k] * wcs[k * 32 + h2];
    int s = s0 + r;
    if (h2 < HID)
        EA[(size_t)s * HID + h2] = __builtin_amdgcn_exp2f(K2 * (acc + b1[h2]));
    else
        EB[(size_t)s * HID + (h2 - 16)] = __builtin_amdgcn_exp2f(K2 * acc);
}

// ---------------- staging helpers (128B-row tiles, XOR swizzle; proven) ----------------
template<int NR>
__device__ __forceinline__ void stageR(const u16* src, int ld, int kt,
                                       u16* ldsb, int t)
{
    int kb0 = kt << 7;
    #pragma unroll
    for (int i = 0; i < NR / 32; ++i) {
        int row  = i * 32 + (t >> 3);
        int colb = (((t & 7) ^ ((t >> 3) & 7)) << 4);
        const char* g = (const char*)src + (size_t)row * ((size_t)ld * 2) + kb0 + colb;
        gload16(g, (char*)ldsb + i * 4096 + ((t >> 6) << 10) + ((t & 63) << 4));
    }
}
__device__ __forceinline__ bf16x8 ldfrag(const u16* ldsb, int r, int s) {
    return *(const bf16x8*)((const char*)ldsb + r * 128 + (((s ^ (r & 7))) << 4));
}

// ---------------- Kernel 3: VT_hi[512][4096] = Wv(split) x X_hi^T ----------------
__global__ __launch_bounds__(256, 2) void vgemm_kernel(
    const u16* __restrict__ Ah, const u16* __restrict__ Al,
    const u16* __restrict__ Bh, u16* __restrict__ outH)
{
    constexpr int TOFF = 64 * 64;
    __shared__ __attribute__((aligned(16))) u16 lds[2][3 * TOFF];   // 48 KB
    int t = threadIdx.x;
    int l = t & 63, wid = t >> 6;
    int wm = (wid >> 1) * 32, wn = (wid & 1) * 32;
    int m0 = blockIdx.y * 64, n0 = blockIdx.x * 64;
    const u16* pAh = Ah + (size_t)m0 * EMBED;
    const u16* pAl = Al + (size_t)m0 * EMBED;
    const u16* pBh = Bh + (size_t)n0 * EMBED;
    f32x4 acc[2][2] = {};

    auto STAGE = [&](int buf, int kt) {
        stageR<64>(pAh, EMBED, kt, lds[buf], t);
        stageR<64>(pAl, EMBED, kt, lds[buf] + TOFF, t);
        stageR<64>(pBh, EMBED, kt, lds[buf] + 2 * TOFF, t);
    };
    auto COMPUTE = [&](int buf) {
        #pragma unroll
        for (int kk = 0; kk < 2; ++kk) {
            int sb = (kk << 2) + (l >> 4);
            bf16x8 ah[2], al2[2], bh[2];
            #pragma unroll
            for (int mf = 0; mf < 2; ++mf) {
                int r = wm + mf * 16 + (l & 15);
                ah[mf]  = ldfrag(lds[buf], r, sb);
                al2[mf] = ldfrag(lds[buf] + TOFF, r, sb);
            }
            #pragma unroll
            for (int nf = 0; nf < 2; ++nf)
                bh[nf] = ldfrag(lds[buf] + 2 * TOFF, wn + nf * 16 + (l & 15), sb);
            #pragma unroll
            for (int mf = 0; mf < 2; ++mf)
                #pragma unroll
                for (int nf = 0; nf < 2; ++nf) {
                    acc[mf][nf] = __builtin_amdgcn_mfma_f32_16x16x32_bf16(ah[mf],  bh[nf], acc[mf][nf], 0, 0, 0);
                    acc[mf][nf] = __builtin_amdgcn_mfma_f32_16x16x32_bf16(al2[mf], bh[nf], acc[mf][nf], 0, 0, 0);
                }
        }
    };

    STAGE(0, 0);
    __syncthreads();
    int cur = 0;
    for (int kt = 0; kt + 1 < 8; ++kt) {
        STAGE(cur ^ 1, kt + 1);
        COMPUTE(cur);
        __syncthreads();
        cur ^= 1;
    }
    COMPUTE(cur);

    int cr = (l >> 4) << 2, cc = l & 15;
    #pragma unroll
    for (int mf = 0; mf < 2; ++mf)
        #pragma unroll
        for (int nf = 0; nf < 2; ++nf)
            #pragma unroll
            for (int r = 0; r < 4; ++r)
                outH[(size_t)(m0 + wm + mf * 16 + cr + r) * 4096
                     + n0 + wn + nf * 16 + cc] = f2bf(acc[mf][nf][r]);
}

// ---------------- Kernel 4: fused logits+softmax+PV (EA*EB, reg-prefetched) ----------
// tanh via e = EA*EB (NO exp in inner loop). Fixed-max softmax (bound S0).
// EB rows double-buffered in NAMED registers, loaded one chunk ahead; wave-local V.
// One raw s_barrier per chunk; vmcnt never force-drained (in-order reg-dep waits).
__global__ __launch_bounds__(256, 1) void fused_kernel(
    const float* __restrict__ EA, const float* __restrict__ EB,
    const float* __restrict__ w2, const u16* __restrict__ VT,
    float* __restrict__ out)
{
    __shared__ __attribute__((aligned(16))) u16 Vl[2][4][128 * 32];  // 2buf x wave x 8KB
    __shared__ __attribute__((aligned(16))) u16 Pl[2][2][16 * 40];   // 80B rows
    __shared__ float sred[4][16];
    __shared__ float srow[16];

    const float L2E = 1.4426950408889634f;
    int t = threadIdx.x;
    int l = t & 63, w = t >> 6;
    int n = blockIdx.x;                      // 0..255
    int b = (n >> 1) & 3;
    int m0 = ((((n & 1) << 5) | (n >> 3))) << 4;
    int prow = t & 15, pslot = t >> 4;

    // EA row (16 floats) for q-row m0+prow
    const float4* Er = (const float4*)(EA + (size_t)(b * SEQ + m0 + prow) * HID);
    float4 A0 = Er[0], A1 = Er[1], A2 = Er[2], A3 = Er[3];

    const float4* Wq4 = (const float4*)w2;
    float4 u0 = Wq4[0], u1 = Wq4[1], u2 = Wq4[2], u3 = Wq4[3];
    float Pa1 = -2.f*u0.x, Pa2 = -2.f*u0.y, Pas = Pa1 + Pa2;
    float Pb1 = -2.f*u0.z, Pb2 = -2.f*u0.w, Pbs = Pb1 + Pb2;
    float Pc1 = -2.f*u1.x, Pc2 = -2.f*u1.y, Pcs = Pc1 + Pc2;
    float Pd1 = -2.f*u1.z, Pd2 = -2.f*u1.w, Pds = Pd1 + Pd2;
    float Pe1 = -2.f*u2.x, Pe2 = -2.f*u2.y, Pes = Pe1 + Pe2;
    float Pf1 = -2.f*u2.z, Pf2 = -2.f*u2.w, Pfs = Pf1 + Pf2;
    float Pg1 = -2.f*u3.x, Pg2 = -2.f*u3.y, Pgs = Pg1 + Pg2;
    float Ph1 = -2.f*u3.z, Ph2 = -2.f*u3.w, Phs = Ph1 + Ph2;
    float S0 = fmaxf(Pa1,0.f)+fmaxf(Pa2,0.f)+fmaxf(Pb1,0.f)+fmaxf(Pb2,0.f)
             + fmaxf(Pc1,0.f)+fmaxf(Pc2,0.f)+fmaxf(Pd1,0.f)+fmaxf(Pd2,0.f)
             + fmaxf(Pe1,0.f)+fmaxf(Pe2,0.f)+fmaxf(Pf1,0.f)+fmaxf(Pf2,0.f)
             + fmaxf(Pg1,0.f)+fmaxf(Pg2,0.f)+fmaxf(Ph1,0.f)+fmaxf(Ph2,0.f);

#define PAIR2(ax, ay, bx, by, P1, P2, PS) { \
    float e1 = (ax) * (bx); float e2 = (ay) * (by); \
    float dd = fmaf(e1, e2, e1) + (e2 + 1.0f); \
    float nn = fmaf((P1), e2, (PS)); nn = fmaf((P2), e1, nn); \
    s = fmaf(nn, __builtin_amdgcn_rcpf(dd), s); }

#define CALCLG(LG, v0, v1, v2, v3) { float s = 0.f; \
    PAIR2(A0.x, A0.y, v0.x, v0.y, Pa1, Pa2, Pas) \
    PAIR2(A0.z, A0.w, v0.z, v0.w, Pb1, Pb2, Pbs) \
    PAIR2(A1.x, A1.y, v1.x, v1.y, Pc1, Pc2, Pcs) \
    PAIR2(A1.z, A1.w, v1.z, v1.w, Pd1, Pd2, Pds) \
    PAIR2(A2.x, A2.y, v2.x, v2.y, Pe1, Pe2, Pes) \
    PAIR2(A2.z, A2.w, v2.z, v2.w, Pf1, Pf2, Pfs) \
    PAIR2(A3.x, A3.y, v3.x, v3.y, Pg1, Pg2, Pgs) \
    PAIR2(A3.z, A3.w, v3.z, v3.w, Ph1, Ph2, Phs) \
    LG = s; }

    // wave-local V staging: wave w owns d-rows [128w, 128w+128)
    auto stageV = [&](int buf, int c) {
        size_t colbase = ((size_t)b << 10) + ((size_t)c << 5);
        #pragma unroll
        for (int i = 0; i < 8; ++i) {
            int rl = (i << 4) + (l >> 2);
            int f_ = (rl >> 1) & 3;
            int sl = ((l & 3) - f_) & 3;
            const u16* g = VT + (size_t)((w << 7) + rl) * 4096 + colbase + (sl << 3);
            gload16(g, (char*)&Vl[buf][w][0] + (i << 10) + (l << 4));
        }
    };
    const float* EBB = EB + ((size_t)(b << 10) + (pslot << 1)) * HID;
#define LOADQ(d0,d1,d2,d3,d4,d5,d6,d7, c) { \
    const float4* _p = (const float4*)(EBB + (size_t)((c) << 5) * HID); \
    d0=_p[0]; d1=_p[1]; d2=_p[2]; d3=_p[3]; d4=_p[4]; d5=_p[5]; d6=_p[6]; d7=_p[7]; }

#define CHUNK_BODY(pb, Q0,Q1,Q2,Q3,Q4,Q5,Q6,Q7) { \
    float lg0, lg1; \
    CALCLG(lg0, Q0, Q1, Q2, Q3) \
    CALCLG(lg1, Q4, Q5, Q6, Q7) \
    float p0 = __builtin_amdgcn_exp2f((lg0 - S0) * L2E); \
    float p1 = __builtin_amdgcn_exp2f((lg1 - S0) * L2E); \
    s_part += p0 + p1; \
    u16 h0 = f2bf(p0), lo0 = f2bf(p0 - bf2f(h0)); \
    u16 h1 = f2bf(p1), lo1 = f2bf(p1 - bf2f(h1)); \
    *(ushort2*)((char*)&Pl[pb][0][0] + prow * 80 + pslot * 4) = make_ushort2(h0, h1); \
    *(ushort2*)((char*)&Pl[pb][1][0] + prow * 80 + pslot * 4) = make_ushort2(lo0, lo1); \
    asm volatile("s_waitcnt lgkmcnt(0)" ::: "memory"); \
    __builtin_amdgcn_s_barrier(); \
    __builtin_amdgcn_sched_barrier(0); \
    bf16x8 pah = *(const bf16x8*)((const char*)&Pl[pb][0][0] + (l & 15) * 80 + ((l >> 4) << 4)); \
    bf16x8 pal = *(const bf16x8*)((const char*)&Pl[pb][1][0] + (l & 15) * 80 + ((l >> 4) << 4)); \
    _Pragma("unroll") \
    for (int nf = 0; nf < 8; ++nf) { \
        int rl = (nf << 4) + (l & 15); \
        int phys = ((l >> 4) + ((rl >> 1) & 3)) & 3; \
        bf16x8 vb = *(const bf16x8*)((const char*)&Vl[pb][w][0] + rl * 64 + (phys << 4)); \
        acc[nf] = __builtin_amdgcn_mfma_f32_16x16x32_bf16(pah, vb, acc[nf], 0, 0, 0); \
        acc[nf] = __builtin_amdgcn_mfma_f32_16x16x32_bf16(pal, vb, acc[nf], 0, 0, 0); \
    } \
    __builtin_amdgcn_sched_barrier(0); }

    f32x4 acc[8] = {};
    float s_part = 0.f;
    float4 qa0, qa1, qa2, qa3, qa4, qa5, qa6, qa7;
    float4 qb0, qb1, qb2, qb3, qb4, qb5, qb6, qb7;

    stageV(0, 0);
    LOADQ(qa0,qa1,qa2,qa3,qa4,qa5,qa6,qa7, 0)

    #pragma unroll 1
    for (int cc = 0; cc < 16; ++cc) {
        int c0 = cc << 1;
        // even chunk c0: Pl[0], Vl[0]; prefetch V(c0+1)+EB(c0+1)
        stageV(1, c0 + 1);
        LOADQ(qb0,qb1,qb2,qb3,qb4,qb5,qb6,qb7, c0 + 1)
        CHUNK_BODY(0, qa0,qa1,qa2,qa3,qa4,qa5,qa6,qa7)
        // odd chunk c0+1: Pl[1], Vl[1]; prefetch V(c0+2)+EB(c0+2)
        if (cc < 15) {
            stageV(0, c0 + 2);
            LOADQ(qa0,qa1,qa2,qa3,qa4,qa5,qa6,qa7, c0 + 2)
        }
        CHUNK_BODY(1, qb0,qb1,qb2,qb3,qb4,qb5,qb6,qb7)
    }
#undef CHUNK_BODY
#undef LOADQ
#undef CALCLG
#undef PAIR2

    // row-sum reduce
    float sv = s_part;
    sv += __shfl_xor(sv, 16);
    sv += __shfl_xor(sv, 32);
    if (l < 16) sred[w][l] = sv;
    __syncthreads();
    if (t < 16) srow[t] = (sred[0][t] + sred[1][t]) + (sred[2][t] + sred[3][t]);
    __syncthreads();
    int rr = (l >> 4) << 2;
    float i0 = __fdividef(1.f, srow[rr + 0]);
    float i1 = __fdividef(1.f, srow[rr + 1]);
    float i2 = __fdividef(1.f, srow[rr + 2]);
    float i3 = __fdividef(1.f, srow[rr + 3]);
    #pragma unroll
    for (int nf = 0; nf < 8; ++nf) {
        size_t base = (size_t)(b * SEQ + m0 + rr) * EMBED + (w << 7) + (nf << 4) + (l & 15);
        out[base]             = acc[nf][0] * i0;
        out[base + EMBED]     = acc[nf][1] * i1;
        out[base + 2 * EMBED] = acc[nf][2] * i2;
        out[base + 3 * EMBED] = acc[nf][3] * i3;
    }
}

extern "C" void kernel_launch(void* const* d_in, const int* in_sizes, int n_in,
                              void* d_out, int out_size, void* d_ws, size_t ws_size,
                              hipStream_t stream) {
    const float* x   = (const float*)d_in[0];
    const float* Wq  = (const float*)d_in[1];
    const float* Wk  = (const float*)d_in[2];
    const float* Wvm = (const float*)d_in[3];
    const float* W1  = (const float*)d_in[4];
    const float* b1  = (const float*)d_in[5];
    const float* w2  = (const float*)d_in[6];
    // d_in[7] = b2: softmax shift-invariant, unused.

    char* ws = (char*)d_ws;
    float* WcT   = (float*)(ws + 0);          //    65,536 B
    float* EA    = (float*)(ws + 65536);      //   262,144 B
    float* EB    = (float*)(ws + 327680);     //   262,144 B
    u16*   VT_hi = (u16*)(ws + 589824);       // 4,194,304 B  [512][4096]
    u16*   x_hi  = (u16*)(ws + 4784128);      // 4,194,304 B  [4096][512]
    u16*   wv_hi = (u16*)(ws + 8978432);      //   524,288 B
    u16*   wv_lo = (u16*)(ws + 9502720);      //   524,288 B
    float* out   = (float*)d_out;

    hipLaunchKernelGGL(wc_kernel, dim3(320), dim3(256), 0, stream,
                       Wq, Wk, W1, Wvm, WcT, wv_hi, wv_lo);
    hipLaunchKernelGGL(ab_kernel, dim3(512), dim3(256), 0, stream,
                       x, WcT, b1, EA, EB, x_hi);
    hipLaunchKernelGGL(vgemm_kernel, dim3(64, 8), dim3(256), 0, stream,
                       wv_hi, wv_lo, x_hi, VT_hi);
    hipLaunchKernelGGL(fused_kernel, dim3(256), dim3(256), 0, stream,
                       EA, EB, w2, VT_hi, out);
}

// Round 10
// 75.822 us; speedup vs baseline: 1.3536x; 1.1205x over previous
//
#include <hip/hip_runtime.h>
#include <math.h>
#include <stdint.h>

#define EMBED 512
#define HID 16
#define SEQ 1024

typedef unsigned short u16;
typedef __attribute__((ext_vector_type(8))) __bf16 bf16x8;
typedef __attribute__((ext_vector_type(4))) float f32x4;

__device__ __forceinline__ u16 f2bf(float f) {
    unsigned u = __float_as_uint(f);
    unsigned r = (u + 0x7FFFu + ((u >> 16) & 1u)) >> 16;   // RNE
    return (u16)r;
}
__device__ __forceinline__ float bf2f(u16 h) {
    return __uint_as_float(((unsigned)h) << 16);
}
__device__ __forceinline__ void gload16(const void* g, void* d) {
    __builtin_amdgcn_global_load_lds(
        reinterpret_cast<const __attribute__((address_space(1))) unsigned int*>(
            reinterpret_cast<uintptr_t>(g)),
        reinterpret_cast<__attribute__((address_space(3))) unsigned int*>(
            reinterpret_cast<uintptr_t>(d)),
        16, 0, 0);
}

// ---------------- Kernel 1: fold W1 into Wq/Wk (+fused Wv hi/lo split) ----------------
__global__ __launch_bounds__(256) void wc_kernel(
    const float* __restrict__ Wq, const float* __restrict__ Wk,
    const float* __restrict__ W1, const float* __restrict__ Wvm,
    float* __restrict__ WcT, u16* __restrict__ wv_hi, u16* __restrict__ wv_lo)
{
    __shared__ float w1s[EMBED];
    int t = threadIdx.x;
    if (blockIdx.x >= 64) {
        int i = (blockIdx.x - 64) * 256 + t;       // float4 idx < 65536
        float4 v = ((const float4*)Wvm)[i];
        u16 h0 = f2bf(v.x), h1 = f2bf(v.y), h2 = f2bf(v.z), h3 = f2bf(v.w);
        ((ushort4*)wv_hi)[i] = make_ushort4(h0, h1, h2, h3);
        ((ushort4*)wv_lo)[i] = make_ushort4(f2bf(v.x - bf2f(h0)), f2bf(v.y - bf2f(h1)),
                                            f2bf(v.z - bf2f(h2)), f2bf(v.w - bf2f(h3)));
        return;
    }
    int h2 = blockIdx.x >> 1;         // 0..31
    int ab = h2 >> 4, h = h2 & 15;
    const float* Wmat = ab ? Wk : Wq;
    const float* w1row = W1 + (size_t)h * (2 * EMBED) + ab * EMBED;
    for (int f = t; f < EMBED; f += 256) w1s[f] = w1row[f];
    __syncthreads();
    int e0 = ((blockIdx.x & 1) << 8) + t;
    float acc = 0.f;
    #pragma unroll 16
    for (int f = 0; f < EMBED; ++f)
        acc += w1s[f] * Wmat[(size_t)f * EMBED + e0];
    WcT[(size_t)e0 * 32 + h2] = acc;
}

// ---------------- Kernel 2: EA/EB projections (+fused x_hi split) ----------------
__global__ __launch_bounds__(256) void ab_kernel(
    const float* __restrict__ x, const float* __restrict__ WcT,
    const float* __restrict__ b1,
    float* __restrict__ EA, float* __restrict__ EB, u16* __restrict__ x_hi)
{
    const float K2 = 2.8853900817779268f;   // 2*log2(e)
    __shared__ float xs[8][EMBED];
    __shared__ float wcs[EMBED * 32];
    int t = threadIdx.x;
    int s0 = blockIdx.x * 8;
    #pragma unroll
    for (int i = 0; i < 4; ++i) {
        int idx = t + i * 256;
        int row = idx >> 7, c4 = idx & 127;
        float4 vv = *(const float4*)(x + (size_t)(s0 + row) * EMBED + c4 * 4);
        *(float4*)&xs[row][c4 * 4] = vv;
        u16 h0 = f2bf(vv.x), h1 = f2bf(vv.y), h2 = f2bf(vv.z), h3 = f2bf(vv.w);
        ((ushort4*)x_hi)[(s0 + row) * 128 + c4] = make_ushort4(h0, h1, h2, h3);
    }
    #pragma unroll
    for (int i = 0; i < 16; ++i) {
        int idx = t + i * 256;
        ((float4*)wcs)[idx] = ((const float4*)WcT)[idx];
    }
    __syncthreads();
    int r = t >> 5, h2 = t & 31;
    const float* xr = xs[r];
    float acc = 0.f;
    #pragma unroll 8
    for (int k = 0; k < EMBED; ++k)
        acc += xr[k] * wcs[k * 32 + h2];
    int s = s0 + r;
    if (h2 < HID)
        EA[(size_t)s * HID + h2] = __builtin_amdgcn_exp2f(K2 * (acc + b1[h2]));
    else
        EB[(size_t)s * HID + (h2 - 16)] = __builtin_amdgcn_exp2f(K2 * acc);
}

// ---------------- staging helpers (128B-row tiles, XOR swizzle; proven) ----------------
template<int NR>
__device__ __forceinline__ void stageR(const u16* src, int ld, int kt,
                                       u16* ldsb, int t)
{
    int kb0 = kt << 7;
    #pragma unroll
    for (int i = 0; i < NR / 32; ++i) {
        int row  = i * 32 + (t >> 3);
        int colb = (((t & 7) ^ ((t >> 3) & 7)) << 4);
        const char* g = (const char*)src + (size_t)row * ((size_t)ld * 2) + kb0 + colb;
        gload16(g, (char*)ldsb + i * 4096 + ((t >> 6) << 10) + ((t & 63) << 4));
    }
}
__device__ __forceinline__ bf16x8 ldfrag(const u16* ldsb, int r, int s) {
    return *(const bf16x8*)((const char*)ldsb + r * 128 + (((s ^ (r & 7))) << 4));
}

// ---------------- Kernel 3: VT_hi[512][4096] = Wv(split) x X_hi^T ----------------
// Single 24KB buffer, 2+ blocks/CU co-resident (m97-style implicit overlap).
__global__ __launch_bounds__(256, 4) void vgemm_kernel(
    const u16* __restrict__ Ah, const u16* __restrict__ Al,
    const u16* __restrict__ Bh, u16* __restrict__ outH)
{
    constexpr int TOFF = 64 * 64;
    __shared__ __attribute__((aligned(16))) u16 lds[3 * TOFF];   // 24 KB
    int t = threadIdx.x;
    int l = t & 63, wid = t >> 6;
    int wm = (wid >> 1) * 32, wn = (wid & 1) * 32;
    int m0 = blockIdx.y * 64, n0 = blockIdx.x * 64;
    const u16* pAh = Ah + (size_t)m0 * EMBED;
    const u16* pAl = Al + (size_t)m0 * EMBED;
    const u16* pBh = Bh + (size_t)n0 * EMBED;
    f32x4 acc[2][2] = {};

    for (int kt = 0; kt < 8; ++kt) {
        stageR<64>(pAh, EMBED, kt, lds, t);
        stageR<64>(pAl, EMBED, kt, lds + TOFF, t);
        stageR<64>(pBh, EMBED, kt, lds + 2 * TOFF, t);
        __syncthreads();
        #pragma unroll
        for (int kk = 0; kk < 2; ++kk) {
            int sb = (kk << 2) + (l >> 4);
            bf16x8 ah[2], al2[2], bh[2];
            #pragma unroll
            for (int mf = 0; mf < 2; ++mf) {
                int r = wm + mf * 16 + (l & 15);
                ah[mf]  = ldfrag(lds, r, sb);
                al2[mf] = ldfrag(lds + TOFF, r, sb);
            }
            #pragma unroll
            for (int nf = 0; nf < 2; ++nf)
                bh[nf] = ldfrag(lds + 2 * TOFF, wn + nf * 16 + (l & 15), sb);
            #pragma unroll
            for (int mf = 0; mf < 2; ++mf)
                #pragma unroll
                for (int nf = 0; nf < 2; ++nf) {
                    acc[mf][nf] = __builtin_amdgcn_mfma_f32_16x16x32_bf16(ah[mf],  bh[nf], acc[mf][nf], 0, 0, 0);
                    acc[mf][nf] = __builtin_amdgcn_mfma_f32_16x16x32_bf16(al2[mf], bh[nf], acc[mf][nf], 0, 0, 0);
                }
        }
        __syncthreads();
    }

    int cr = (l >> 4) << 2, cc = l & 15;
    #pragma unroll
    for (int mf = 0; mf < 2; ++mf)
        #pragma unroll
        for (int nf = 0; nf < 2; ++nf)
            #pragma unroll
            for (int r = 0; r < 4; ++r)
                outH[(size_t)(m0 + wm + mf * 16 + cr + r) * 4096
                     + n0 + wn + nf * 16 + cc] = f2bf(acc[mf][nf][r]);
}

// ---------------- Kernel 4: fused logits+softmax+PV (8 waves, 1 logit/thread) -------
// 512 threads = 8 waves = 2 waves/SIMD: wave-level latency hiding (m114).
// tanh via e = EA*EB; fixed-max softmax (bound S0); wave-local V (64 d-rows/wave);
// EB double-buffered in NAMED regs one chunk ahead; ONE raw s_barrier per chunk.
__global__ __launch_bounds__(512, 1) void fused_kernel(
    const float* __restrict__ EA, const float* __restrict__ EB,
    const float* __restrict__ w2, const u16* __restrict__ VT,
    float* __restrict__ out)
{
    __shared__ __attribute__((aligned(16))) u16 Vl[2][8][64 * 32];   // 2buf x wave x 4KB
    __shared__ __attribute__((aligned(16))) u16 Pl[2][2][16 * 40];   // 80B rows
    __shared__ float sred[8][16];
    __shared__ float srow[16];

    const float L2E = 1.4426950408889634f;
    int t = threadIdx.x;
    int l = t & 63, w = t >> 6;              // 8 waves
    int n = blockIdx.x;                      // 0..255
    int b = (n >> 1) & 3;                    // batch b -> 2 XCDs (L2-resident VT slice)
    int m0 = ((((n & 1) << 5) | (n >> 3))) << 4;
    int prow = t & 15, pslot = t >> 4;       // pslot 0..31: one logit per thread

    const float4* Er = (const float4*)(EA + (size_t)(b * SEQ + m0 + prow) * HID);
    float4 A0 = Er[0], A1 = Er[1], A2 = Er[2], A3 = Er[3];

    const float4* Wq4 = (const float4*)w2;
    float4 u0 = Wq4[0], u1 = Wq4[1], u2 = Wq4[2], u3 = Wq4[3];
    float Pa1 = -2.f*u0.x, Pa2 = -2.f*u0.y, Pas = Pa1 + Pa2;
    float Pb1 = -2.f*u0.z, Pb2 = -2.f*u0.w, Pbs = Pb1 + Pb2;
    float Pc1 = -2.f*u1.x, Pc2 = -2.f*u1.y, Pcs = Pc1 + Pc2;
    float Pd1 = -2.f*u1.z, Pd2 = -2.f*u1.w, Pds = Pd1 + Pd2;
    float Pe1 = -2.f*u2.x, Pe2 = -2.f*u2.y, Pes = Pe1 + Pe2;
    float Pf1 = -2.f*u2.z, Pf2 = -2.f*u2.w, Pfs = Pf1 + Pf2;
    float Pg1 = -2.f*u3.x, Pg2 = -2.f*u3.y, Pgs = Pg1 + Pg2;
    float Ph1 = -2.f*u3.z, Ph2 = -2.f*u3.w, Phs = Ph1 + Ph2;
    float S0 = fmaxf(Pa1,0.f)+fmaxf(Pa2,0.f)+fmaxf(Pb1,0.f)+fmaxf(Pb2,0.f)
             + fmaxf(Pc1,0.f)+fmaxf(Pc2,0.f)+fmaxf(Pd1,0.f)+fmaxf(Pd2,0.f)
             + fmaxf(Pe1,0.f)+fmaxf(Pe2,0.f)+fmaxf(Pf1,0.f)+fmaxf(Pf2,0.f)
             + fmaxf(Pg1,0.f)+fmaxf(Pg2,0.f)+fmaxf(Ph1,0.f)+fmaxf(Ph2,0.f);

#define PAIR2(ax, ay, bx, by, P1, P2, PS) { \
    float e1 = (ax) * (bx); float e2 = (ay) * (by); \
    float dd = fmaf(e1, e2, e1) + (e2 + 1.0f); \
    float nn = fmaf((P1), e2, (PS)); nn = fmaf((P2), e1, nn); \
    s = fmaf(nn, __builtin_amdgcn_rcpf(dd), s); }

#define CALCLG(LG, v0, v1, v2, v3) { float s = 0.f; \
    PAIR2(A0.x, A0.y, v0.x, v0.y, Pa1, Pa2, Pas) \
    PAIR2(A0.z, A0.w, v0.z, v0.w, Pb1, Pb2, Pbs) \
    PAIR2(A1.x, A1.y, v1.x, v1.y, Pc1, Pc2, Pcs) \
    PAIR2(A1.z, A1.w, v1.z, v1.w, Pd1, Pd2, Pds) \
    PAIR2(A2.x, A2.y, v2.x, v2.y, Pe1, Pe2, Pes) \
    PAIR2(A2.z, A2.w, v2.z, v2.w, Pf1, Pf2, Pfs) \
    PAIR2(A3.x, A3.y, v3.x, v3.y, Pg1, Pg2, Pgs) \
    PAIR2(A3.z, A3.w, v3.z, v3.w, Ph1, Ph2, Phs) \
    LG = s; }

    // wave-local V staging: wave w owns d-rows [64w, 64w+64)
    auto stageV = [&](int buf, int c) {
        size_t colbase = ((size_t)b << 10) + ((size_t)c << 5);
        #pragma unroll
        for (int i = 0; i < 4; ++i) {
            int rl = (i << 4) + (l >> 2);                    // 0..63
            int f_ = (rl >> 1) & 3;
            int sl = ((l & 3) - f_) & 3;                     // inverse slot rotation
            const u16* g = VT + (size_t)((w << 6) + rl) * 4096 + colbase + (sl << 3);
            gload16(g, (char*)&Vl[buf][w][0] + (i << 10) + (l << 4));
        }
    };
    const float* EBB = EB + ((size_t)(b << 10) + pslot) * HID;
#define LOADQ(d0,d1,d2,d3, c) { \
    const float4* _p = (const float4*)(EBB + (size_t)((c) << 5) * HID); \
    d0=_p[0]; d1=_p[1]; d2=_p[2]; d3=_p[3]; }

#define CHUNK_BODY(pb, Q0,Q1,Q2,Q3) { \
    float lg0; \
    CALCLG(lg0, Q0, Q1, Q2, Q3) \
    float p0 = __builtin_amdgcn_exp2f((lg0 - S0) * L2E); \
    s_part += p0; \
    u16 h0 = f2bf(p0), lo0 = f2bf(p0 - bf2f(h0)); \
    *(u16*)((char*)&Pl[pb][0][0] + prow * 80 + pslot * 2) = h0; \
    *(u16*)((char*)&Pl[pb][1][0] + prow * 80 + pslot * 2) = lo0; \
    asm volatile("s_waitcnt lgkmcnt(0)" ::: "memory"); \
    __builtin_amdgcn_s_barrier(); \
    __builtin_amdgcn_sched_barrier(0); \
    bf16x8 pah = *(const bf16x8*)((const char*)&Pl[pb][0][0] + (l & 15) * 80 + ((l >> 4) << 4)); \
    bf16x8 pal = *(const bf16x8*)((const char*)&Pl[pb][1][0] + (l & 15) * 80 + ((l >> 4) << 4)); \
    _Pragma("unroll") \
    for (int nf = 0; nf < 4; ++nf) { \
        int rl = (nf << 4) + (l & 15); \
        int phys = ((l >> 4) + ((rl >> 1) & 3)) & 3; \
        bf16x8 vb = *(const bf16x8*)((const char*)&Vl[pb][w][0] + rl * 64 + (phys << 4)); \
        acc[nf] = __builtin_amdgcn_mfma_f32_16x16x32_bf16(pah, vb, acc[nf], 0, 0, 0); \
        acc[nf] = __builtin_amdgcn_mfma_f32_16x16x32_bf16(pal, vb, acc[nf], 0, 0, 0); \
    } \
    __builtin_amdgcn_sched_barrier(0); }

    f32x4 acc[4] = {};
    float s_part = 0.f;
    float4 qa0, qa1, qa2, qa3;
    float4 qb0, qb1, qb2, qb3;

    stageV(0, 0);
    LOADQ(qa0,qa1,qa2,qa3, 0)

    #pragma unroll 1
    for (int cc = 0; cc < 16; ++cc) {
        int c0 = cc << 1;
        stageV(1, c0 + 1);
        LOADQ(qb0,qb1,qb2,qb3, c0 + 1)
        CHUNK_BODY(0, qa0,qa1,qa2,qa3)
        if (cc < 15) {
            stageV(0, c0 + 2);
            LOADQ(qa0,qa1,qa2,qa3, c0 + 2)
        }
        CHUNK_BODY(1, qb0,qb1,qb2,qb3)
    }
#undef CHUNK_BODY
#undef LOADQ
#undef CALCLG
#undef PAIR2

    // row-sum: lanes sharing prow within wave (xor 16, 32), then across 8 waves
    float sv = s_part;
    sv += __shfl_xor(sv, 16);
    sv += __shfl_xor(sv, 32);
    if (l < 16) sred[w][l] = sv;
    __syncthreads();
    if (t < 16) srow[t] = ((sred[0][t] + sred[1][t]) + (sred[2][t] + sred[3][t]))
                        + ((sred[4][t] + sred[5][t]) + (sred[6][t] + sred[7][t]));
    __syncthreads();
    int rr = (l >> 4) << 2;
    float i0 = __fdividef(1.f, srow[rr + 0]);
    float i1 = __fdividef(1.f, srow[rr + 1]);
    float i2 = __fdividef(1.f, srow[rr + 2]);
    float i3 = __fdividef(1.f, srow[rr + 3]);
    #pragma unroll
    for (int nf = 0; nf < 4; ++nf) {
        size_t base = (size_t)(b * SEQ + m0 + rr) * EMBED + (w << 6) + (nf << 4) + (l & 15);
        out[base]             = acc[nf][0] * i0;
        out[base + EMBED]     = acc[nf][1] * i1;
        out[base + 2 * EMBED] = acc[nf][2] * i2;
        out[base + 3 * EMBED] = acc[nf][3] * i3;
    }
}

extern "C" void kernel_launch(void* const* d_in, const int* in_sizes, int n_in,
                              void* d_out, int out_size, void* d_ws, size_t ws_size,
                              hipStream_t stream) {
    const float* x   = (const float*)d_in[0];
    const float* Wq  = (const float*)d_in[1];
    const float* Wk  = (const float*)d_in[2];
    const float* Wvm = (const float*)d_in[3];
    const float* W1  = (const float*)d_in[4];
    const float* b1  = (const float*)d_in[5];
    const float* w2  = (const float*)d_in[6];
    // d_in[7] = b2: softmax shift-invariant, unused.

    char* ws = (char*)d_ws;
    float* WcT   = (float*)(ws + 0);          //    65,536 B
    float* EA    = (float*)(ws + 65536);      //   262,144 B
    float* EB    = (float*)(ws + 327680);     //   262,144 B
    u16*   VT_hi = (u16*)(ws + 589824);       // 4,194,304 B  [512][4096]
    u16*   x_hi  = (u16*)(ws + 4784128);      // 4,194,304 B  [4096][512]
    u16*   wv_hi = (u16*)(ws + 8978432);      //   524,288 B
    u16*   wv_lo = (u16*)(ws + 9502720);      //   524,288 B
    float* out   = (float*)d_out;

    hipLaunchKernelGGL(wc_kernel, dim3(320), dim3(256), 0, stream,
                       Wq, Wk, W1, Wvm, WcT, wv_hi, wv_lo);
    hipLaunchKernelGGL(ab_kernel, dim3(512), dim3(256), 0, stream,
                       x, WcT, b1, EA, EB, x_hi);
    hipLaunchKernelGGL(vgemm_kernel, dim3(64, 8), dim3(256), 0, stream,
                       wv_hi, wv_lo, x_hi, VT_hi);
    hipLaunchKernelGGL(fused_kernel, dim3(256), dim3(512), 0, stream,
                       EA, EB, w2, VT_hi, out);
}